// Round 10
// baseline (89.689 us; speedup 1.0000x reference)
//
#include <hip/hip_runtime.h>
#include <hip/hip_bf16.h>

typedef short bf16x8 __attribute__((ext_vector_type(8)));
typedef float f32x4 __attribute__((ext_vector_type(4)));
typedef unsigned short u16;
typedef unsigned short u16x4 __attribute__((ext_vector_type(4)));
typedef unsigned short u16x8 __attribute__((ext_vector_type(8)));

#define FINF 1.0e12f

__device__ __forceinline__ u16 f2b(float f) {
  union { float f; unsigned int u; } x; x.f = f;
  unsigned int r = x.u + 0x7fffu + ((x.u >> 16) & 1u);
  return (u16)(r >> 16);
}

// Kernel 0: W1 (1024x128 f32) -> bf16 in MFMA B-fragment order.
__global__ __launch_bounds__(256) void k0_w1frag(const float* __restrict__ W1,
                                                 u16* __restrict__ w1f) {
  int idx = blockIdx.x * 256 + threadIdx.x;   // 0..131071
  int k = idx >> 7, c = idx & 127;
  float v = W1[idx];
  int chunk = k >> 6, kk = k & 63;
  int ks = kk >> 5, km = kk & 31, kg = km >> 3, i = km & 7;
  int nt = c >> 4, ln = c & 15;
  int dst = chunk * 8192 + (nt * 2 + ks) * 512 + (kg * 16 + ln) * 8 + i;
  w1f[dst] = f2b(v);
}

// Kernel 1: identical to round 9 (512 threads, double-buffered).
__global__ __launch_bounds__(512) void k1_prep(
    const float* __restrict__ inputs, const u16* __restrict__ w1f,
    const float* __restrict__ b1, const float* __restrict__ W2,
    const float* __restrict__ b2,
    u16* __restrict__ qw, u16* __restrict__ kw,
    float* __restrict__ biasE, float* __restrict__ biasO) {
  __shared__ __align__(16) char smem[53632];
  float* w2t = (float*)(smem + 40960);  // [c][k] pad 132
  float* xt  = (float*)smem;            // 32 x 132 f32 (alias, post-loop)

  int t = threadIdx.x;
  int lane = t & 63, w = t >> 6;        // 8 waves
  int r0 = blockIdx.x * 32;
  int b = r0 >> 9, l0 = r0 & 511;

  #pragma unroll
  for (int i = 0; i < 6; ++i) {
    int idx = t + i * 512;
    int k = idx / 24, c = idx - k * 24;
    w2t[c * 132 + k] = W2[idx];
  }

  f32x4 acc[2];
  acc[0] = (f32x4){0.f, 0.f, 0.f, 0.f};
  acc[1] = (f32x4){0.f, 0.f, 0.f, 0.f};

  int wr = (w & 1) * 16;
  int wnt = (w >> 1) * 2;

  bool doA = (t < 256);
  int arow_s = (t & 255) >> 3;
  const float* ain = &inputs[(size_t)(r0 + arow_s) * 1024 + (t & 7) * 8];
  int abyt = (arow_s * 128 + (t & 7) * 16) ^ ((arow_s & 7) << 4);
  const float4* wsrcAll = (const float4*)w1f;

  float4 a0, a1;
  if (doA) { a0 = *(const float4*)(ain); a1 = *(const float4*)(ain + 4); }
  float4 wr0 = wsrcAll[t];
  float4 wr1 = wsrcAll[t + 512];
  {
    if (doA) {
      u16x8 av;
      av[0] = f2b(a0.x); av[1] = f2b(a0.y); av[2] = f2b(a0.z); av[3] = f2b(a0.w);
      av[4] = f2b(a1.x); av[5] = f2b(a1.y); av[6] = f2b(a1.z); av[7] = f2b(a1.w);
      *(u16x8*)(smem + abyt) = av;
    }
    float4* wd = (float4*)(smem + 8192);
    wd[t] = wr0; wd[t + 512] = wr1;
  }
  __syncthreads();

  for (int ch = 0; ch < 16; ++ch) {
    if (ch < 15) {
      if (doA) {
        a0 = *(const float4*)(ain + (ch + 1) * 64);
        a1 = *(const float4*)(ain + (ch + 1) * 64 + 4);
      }
      const float4* wsrc = wsrcAll + (ch + 1) * 1024;
      wr0 = wsrc[t]; wr1 = wsrc[t + 512];
    }
    {
      const char* Ab = smem + (ch & 1) * 4096;
      const u16* Wb = (const u16*)(smem + 8192 + (ch & 1) * 16384);
      int arow = wr + (lane & 15);
      int hi = lane >> 4;
      #pragma unroll
      for (int ks = 0; ks < 2; ++ks) {
        int cb = ks * 64 + hi * 16;
        bf16x8 a = *(const bf16x8*)(Ab + ((arow * 128 + cb) ^ ((arow & 7) << 4)));
        #pragma unroll
        for (int nti = 0; nti < 2; ++nti) {
          int nt = wnt + nti;
          bf16x8 bb = *(const bf16x8*)&Wb[((nt * 2 + ks) * 64 + lane) * 8];
          acc[nti] = __builtin_amdgcn_mfma_f32_16x16x32_bf16(a, bb, acc[nti], 0, 0, 0);
        }
      }
    }
    if (ch < 15) {
      int q = (ch + 1) & 1;
      if (doA) {
        u16x8 av;
        av[0] = f2b(a0.x); av[1] = f2b(a0.y); av[2] = f2b(a0.z); av[3] = f2b(a0.w);
        av[4] = f2b(a1.x); av[5] = f2b(a1.y); av[6] = f2b(a1.z); av[7] = f2b(a1.w);
        *(u16x8*)(smem + q * 4096 + abyt) = av;
      }
      float4* wd = (float4*)(smem + 8192 + q * 16384);
      wd[t] = wr0; wd[t + 512] = wr1;
    }
    __syncthreads();
  }
  __syncthreads();

  #pragma unroll
  for (int nti = 0; nti < 2; ++nti) {
    int c = (wnt + nti) * 16 + (lane & 15);
    float b1v = b1[c];
    #pragma unroll
    for (int r = 0; r < 4; ++r) {
      int row = wr + ((lane >> 4) << 2) + r;
      xt[row * 132 + c] = acc[nti][r] + b1v;
    }
  }
  __syncthreads();

  {
    int r = t >> 4, jb = (t & 15) * 2;
    int l = l0 + r;
    float fl = (float)l;
    u16x4 qv, kv;
    #pragma unroll
    for (int p = 0; p < 2; ++p) {
      int j = jb + p;
      float4 x4 = *(const float4*)&xt[r * 132 + 4 * j];
      float invf = exp2f(-0.4152410118609203f * (float)j);  // 10000^(-j/32)
      float ang = fl * invf;
      float rev = ang * 0.15915494309189535f;
      rev = rev - floorf(rev);
      float sv, cv;
      __sincosf(rev * 6.2831853071795864f, &sv, &cv);
      qv[2 * p] = f2b(x4.x * cv - x4.z * sv);
      qv[2 * p + 1] = f2b(x4.x * sv + x4.z * cv);
      kv[2 * p] = f2b(x4.y * cv - x4.w * sv);
      kv[2 * p + 1] = f2b(x4.y * sv + x4.w * cv);
    }
    size_t base = ((size_t)(b * 512 + l)) * 64 + jb * 2;
    *(u16x4*)&qw[base] = qv;
    *(u16x4*)&kw[base] = kv;
  }

  if (t < 384) {
    int c = t >> 4;
    int rg = (t & 15) * 2;
    float s0 = b2[c], s1 = s0;
    #pragma unroll
    for (int k4 = 0; k4 < 32; ++k4) {
      float4 wv = *(const float4*)&w2t[c * 132 + k4 * 4];
      float4 x0 = *(const float4*)&xt[(rg + 0) * 132 + k4 * 4];
      float4 x1 = *(const float4*)&xt[(rg + 1) * 132 + k4 * 4];
      s0 += x0.x * wv.x + x0.y * wv.y + x0.z * wv.z + x0.w * wv.w;
      s1 += x1.x * wv.x + x1.y * wv.y + x1.z * wv.z + x1.w * wv.w;
    }
    int h = c >> 1;
    size_t o = ((size_t)(b * 12 + h)) * 512 + l0 + rg;
    float2 sv = {s0 * 0.5f, s1 * 0.5f};
    if (c & 1) *(float2*)&biasO[o] = sv;
    else       *(float2*)&biasE[o] = sv;
  }
}

// Kernel 2: identical to round 9. Launched TWICE this round (idempotent) as a
// timing diagnostic: dur_total - 57.4 = k2 duration.
__global__ __launch_bounds__(256) void k2_main(
    const u16* __restrict__ qw, const u16* __restrict__ kw,
    const float* __restrict__ biasE, const float* __restrict__ biasO,
    const float* __restrict__ amask, float* __restrict__ out) {
  __shared__ char smem[24448];
  u16* Q = (u16*)smem;              // 8KB swizzled [m][d]
  u16* K = (u16*)(smem + 8192);     // 8KB swizzled [n][d]
  float* qkL = (float*)smem;        // 64x68 f32 (17408B) — overlaps Q/K (dead)
  float* BN = (float*)(smem + 17408);
  float* BM = (float*)(smem + 17408 + 3264);
  float* AMm = (float*)(smem + 17408 + 6528);
  float* AMn = AMm + 64;

  int t = threadIdx.x;
  int lane = t & 63, w = t >> 6;
  int n0 = blockIdx.x * 64, m0 = blockIdx.y * 64, b = blockIdx.z;
  bool skip = (m0 >= n0 + 64);  // fully below diagonal

  if (!skip) {
    int row = t >> 2, sg = t & 3;
    const u16x8* qsrc = (const u16x8*)&qw[((size_t)(b * 512 + m0 + row)) * 64 + sg * 16];
    u16x8 q0 = qsrc[0], q1 = qsrc[1];
    const u16x8* ksrc = (const u16x8*)&kw[((size_t)(b * 512 + n0 + row)) * 64 + sg * 16];
    u16x8 k0v = ksrc[0], k1v = ksrc[1];
    int swz = (row & 7) << 4;
    int byt = row * 128 + sg * 32;
    *(u16x8*)((char*)Q + ((byt) ^ swz)) = q0;
    *(u16x8*)((char*)Q + ((byt + 16) ^ swz)) = q1;
    *(u16x8*)((char*)K + ((byt) ^ swz)) = k0v;
    *(u16x8*)((char*)K + ((byt + 16) ^ swz)) = k1v;
  }
  if (t < 192) {
    int h = t >> 4, kq = t & 15;
    *(float4*)&BN[h * 68 + kq * 4] =
        *(const float4*)&biasE[((size_t)(b * 12 + h)) * 512 + n0 + kq * 4];
    *(float4*)&BM[h * 68 + kq * 4] =
        *(const float4*)&biasO[((size_t)(b * 12 + h)) * 512 + m0 + kq * 4];
  } else if (t < 224) {
    int i = t - 192;
    if (i < 16) *(float4*)&AMm[i * 4] = *(const float4*)&amask[b * 512 + m0 + i * 4];
    else { int ii = i - 16; *(float4*)&AMn[ii * 4] = *(const float4*)&amask[b * 512 + n0 + ii * 4]; }
  }
  __syncthreads();

  if (!skip) {
    f32x4 acc[4];
    #pragma unroll
    for (int nt = 0; nt < 4; ++nt) acc[nt] = (f32x4){0.f, 0.f, 0.f, 0.f};
    int mrow = w * 16 + (lane & 15);
    int hi = lane >> 4;
    #pragma unroll
    for (int ks = 0; ks < 2; ++ks) {
      int cb = ks * 64 + hi * 16;
      bf16x8 a = *(const bf16x8*)((const char*)Q +
                                  ((mrow * 128 + cb) ^ ((mrow & 7) << 4)));
      #pragma unroll
      for (int nt = 0; nt < 4; ++nt) {
        int nr = nt * 16 + (lane & 15);
        bf16x8 bb = *(const bf16x8*)((const char*)K +
                                     ((nr * 128 + cb) ^ ((nr & 7) << 4)));
        acc[nt] = __builtin_amdgcn_mfma_f32_16x16x32_bf16(a, bb, acc[nt], 0, 0, 0);
      }
    }
    __syncthreads();  // Q/K dead; safe to overwrite with qkL
    #pragma unroll
    for (int nt = 0; nt < 4; ++nt)
      #pragma unroll
      for (int r = 0; r < 4; ++r)
        qkL[(w * 16 + hi * 4 + r) * 68 + nt * 16 + (lane & 15)] = acc[nt][r];
    __syncthreads();
  }

  int a15 = t & 15, mb = t >> 4;  // thread owns n = 4*a15+j, m = mb+16*mi
  float amn0 = AMn[a15 * 4 + 0], amn1 = AMn[a15 * 4 + 1];
  float amn2 = AMn[a15 * 4 + 2], amn3 = AMn[a15 * 4 + 3];
  float vals[4][4];
  #pragma unroll
  for (int mi = 0; mi < 4; ++mi) {
    int m = mb + 16 * mi;
    int mg = m0 + m;
    float amm = AMm[m];
    int ng = n0 + a15 * 4;
    float p0 = (1.f - amm * amn0) * FINF + ((mg > ng + 0) ? FINF : 0.f);
    float p1 = (1.f - amm * amn1) * FINF + ((mg > ng + 1) ? FINF : 0.f);
    float p2 = (1.f - amm * amn2) * FINF + ((mg > ng + 2) ? FINF : 0.f);
    float p3 = (1.f - amm * amn3) * FINF + ((mg > ng + 3) ? FINF : 0.f);
    if (!skip) {
      float4 qk = *(const float4*)&qkL[m * 68 + a15 * 4];
      vals[mi][0] = qk.x * 0.125f - p0;
      vals[mi][1] = qk.y * 0.125f - p1;
      vals[mi][2] = qk.z * 0.125f - p2;
      vals[mi][3] = qk.w * 0.125f - p3;
    } else {
      vals[mi][0] = -p0; vals[mi][1] = -p1; vals[mi][2] = -p2; vals[mi][3] = -p3;
    }
  }

  size_t outbase = (size_t)(b * 12) * 262144 + (size_t)m0 * 512 + n0 + a15 * 4;
  #pragma unroll
  for (int h = 0; h < 12; ++h) {
    float4 bn = *(const float4*)&BN[h * 68 + a15 * 4];
    #pragma unroll
    for (int mi = 0; mi < 4; ++mi) {
      int m = mb + 16 * mi;
      float bm = BM[h * 68 + m];
      float4 v;
      v.x = vals[mi][0] + bn.x + bm;
      v.y = vals[mi][1] + bn.y + bm;
      v.z = vals[mi][2] + bn.z + bm;
      v.w = vals[mi][3] + bn.w + bm;
      *(float4*)&out[outbase + (size_t)h * 262144 + (size_t)m * 512] = v;
    }
  }
}

extern "C" void kernel_launch(void* const* d_in, const int* in_sizes, int n_in,
                              void* d_out, int out_size, void* d_ws, size_t ws_size,
                              hipStream_t stream) {
  const float* inputs = (const float*)d_in[0];
  const float* amask  = (const float*)d_in[1];
  const float* W1     = (const float*)d_in[2];
  const float* b1     = (const float*)d_in[3];
  const float* W2     = (const float*)d_in[4];
  const float* b2     = (const float*)d_in[5];
  float* out = (float*)d_out;

  char* ws = (char*)d_ws;
  u16* qw      = (u16*)(ws);                            // 1 MB
  u16* kw      = (u16*)(ws + (1u << 20));               // 1 MB
  float* biasE = (float*)(ws + (2u << 20));             // 384 KB
  float* biasO = (float*)(ws + (2u << 20) + 393216u);   // 384 KB
  u16* w1f     = (u16*)(ws + (2u << 20) + 786432u);     // 256 KB

  k0_w1frag<<<512, 256, 0, stream>>>(W1, w1f);
  k1_prep<<<256, 512, 0, stream>>>(inputs, w1f, b1, W2, b2, qw, kw, biasE, biasO);
  // DIAGNOSTIC: k2 launched twice (idempotent). k2_dur = total - 57.4.
  k2_main<<<dim3(8, 8, 16), 256, 0, stream>>>(qw, kw, biasE, biasO, amask, out);
  k2_main<<<dim3(8, 8, 16), 256, 0, stream>>>(qw, kw, biasE, biasO, amask, out);
}

// Round 11
// 55.851 us; speedup vs baseline: 1.6058x; 1.6058x over previous
//
#include <hip/hip_runtime.h>
#include <hip/hip_bf16.h>

typedef short bf16x8 __attribute__((ext_vector_type(8)));
typedef float f32x4 __attribute__((ext_vector_type(4)));
typedef unsigned short u16;
typedef unsigned short u16x4 __attribute__((ext_vector_type(4)));
typedef unsigned short u16x8 __attribute__((ext_vector_type(8)));

#define FINF 1.0e12f

__device__ __forceinline__ u16 f2b(float f) {
  union { float f; unsigned int u; } x; x.f = f;
  unsigned int r = x.u + 0x7fffu + ((x.u >> 16) & 1u);
  return (u16)(r >> 16);
}

// Kernel 0: W1 (1024x128 f32) -> bf16 in MFMA B-fragment order.
__global__ __launch_bounds__(256) void k0_w1frag(const float* __restrict__ W1,
                                                 u16* __restrict__ w1f) {
  int idx = blockIdx.x * 256 + threadIdx.x;   // 0..131071
  int k = idx >> 7, c = idx & 127;
  float v = W1[idx];
  int chunk = k >> 6, kk = k & 63;
  int ks = kk >> 5, km = kk & 31, kg = km >> 3, i = km & 7;
  int nt = c >> 4, ln = c & 15;
  int dst = chunk * 8192 + (nt * 2 + ks) * 512 + (kg * 16 + ln) * 8 + i;
  w1f[dst] = f2b(v);
}

// Kernel 1: 512 blocks x 16 rows, 256 threads (4 waves). TWO independent
// blocks per CU -> one block's compute hides the other's barrier/vmcnt stall.
// Double-buffered A/W tiles, one barrier per chunk.
// smem: Al[2] @0/2048 | Wl[2] @4096/20480 | w2t @36864 (12672B).
// xt (8448B) aliases @0 after the K-loop.
__global__ __launch_bounds__(256) void k1_prep(
    const float* __restrict__ inputs, const u16* __restrict__ w1f,
    const float* __restrict__ b1, const float* __restrict__ W2,
    const float* __restrict__ b2,
    u16* __restrict__ qw, u16* __restrict__ kw,
    float* __restrict__ biasE, float* __restrict__ biasO) {
  __shared__ __align__(16) char smem[49536];
  float* w2t = (float*)(smem + 36864);  // [c][k] pad 132
  float* xt  = (float*)smem;            // 16 x 132 f32 (alias, post-loop)

  int t = threadIdx.x;
  int lane = t & 63, w = t >> 6;        // 4 waves
  int r0 = blockIdx.x * 16;
  int b = r0 >> 9, l0 = r0 & 511;

  // stage W2^T (3072 elems, 12 per thread)
  #pragma unroll
  for (int i = 0; i < 12; ++i) {
    int idx = t + i * 256;
    int k = idx / 24, c = idx - k * 24;
    w2t[c * 132 + k] = W2[idx];
  }

  f32x4 acc[2];
  acc[0] = (f32x4){0.f, 0.f, 0.f, 0.f};
  acc[1] = (f32x4){0.f, 0.f, 0.f, 0.f};

  int wnt = w * 2;             // wave's first nt (2 nts = 32 cols)

  // A staging: thread loads one float4 (4 f32) -> u16x4 (8B).
  int arow_s = t >> 4;                   // 0..15
  int aseg = t & 15;                     // 16 segs x 8B = 128B row
  const float* ain = &inputs[(size_t)(r0 + arow_s) * 1024 + aseg * 4];
  int abyt = (arow_s * 128 + aseg * 8) ^ ((arow_s & 7) << 4);
  const float4* wsrcAll = (const float4*)w1f;

  // ---- prologue: load+stage chunk 0 into buffer 0 ----
  float4 a0 = *(const float4*)(ain);
  float4 wr0 = wsrcAll[t];
  float4 wr1 = wsrcAll[t + 256];
  float4 wr2 = wsrcAll[t + 512];
  float4 wr3 = wsrcAll[t + 768];
  {
    u16x4 av;
    av[0] = f2b(a0.x); av[1] = f2b(a0.y); av[2] = f2b(a0.z); av[3] = f2b(a0.w);
    *(u16x4*)(smem + abyt) = av;
    float4* wd = (float4*)(smem + 4096);
    wd[t] = wr0; wd[t + 256] = wr1; wd[t + 512] = wr2; wd[t + 768] = wr3;
  }
  __syncthreads();

  for (int ch = 0; ch < 16; ++ch) {
    if (ch < 15) {
      a0 = *(const float4*)(ain + (ch + 1) * 64);
      const float4* wsrc = wsrcAll + (ch + 1) * 1024;
      wr0 = wsrc[t]; wr1 = wsrc[t + 256]; wr2 = wsrc[t + 512]; wr3 = wsrc[t + 768];
    }
    // MFMA on buffer p = ch&1
    {
      const char* Ab = smem + (ch & 1) * 2048;
      const u16* Wb = (const u16*)(smem + 4096 + (ch & 1) * 16384);
      int arow = lane & 15;
      int hi = lane >> 4;
      #pragma unroll
      for (int ks = 0; ks < 2; ++ks) {
        int cb = ks * 64 + hi * 16;
        bf16x8 a = *(const bf16x8*)(Ab + ((arow * 128 + cb) ^ ((arow & 7) << 4)));
        #pragma unroll
        for (int nti = 0; nti < 2; ++nti) {
          int nt = wnt + nti;
          bf16x8 bb = *(const bf16x8*)&Wb[((nt * 2 + ks) * 64 + lane) * 8];
          acc[nti] = __builtin_amdgcn_mfma_f32_16x16x32_bf16(a, bb, acc[nti], 0, 0, 0);
        }
      }
    }
    if (ch < 15) {
      int q = (ch + 1) & 1;
      u16x4 av;
      av[0] = f2b(a0.x); av[1] = f2b(a0.y); av[2] = f2b(a0.z); av[3] = f2b(a0.w);
      *(u16x4*)(smem + q * 2048 + abyt) = av;
      float4* wd = (float4*)(smem + 4096 + q * 16384);
      wd[t] = wr0; wd[t + 256] = wr1; wd[t + 512] = wr2; wd[t + 768] = wr3;
    }
    __syncthreads();
  }
  __syncthreads();  // all MFMA reads done before xt aliases Al/Wl

  // epilogue: acc -> xt (+ b1). D: col=lane&15, row=(lane>>4)*4+r
  #pragma unroll
  for (int nti = 0; nti < 2; ++nti) {
    int c = (wnt + nti) * 16 + (lane & 15);
    float b1v = b1[c];
    #pragma unroll
    for (int r = 0; r < 4; ++r) {
      int row = ((lane >> 4) << 2) + r;
      xt[row * 132 + c] = acc[nti][r] + b1v;
    }
  }
  __syncthreads();

  // RoPE: thread handles row t>>4, j = (t&15)*2 .. +1 ; outputs bf16
  {
    int r = t >> 4, jb = (t & 15) * 2;
    int l = l0 + r;
    float fl = (float)l;
    u16x4 qv, kv;
    #pragma unroll
    for (int p = 0; p < 2; ++p) {
      int j = jb + p;
      float4 x4 = *(const float4*)&xt[r * 132 + 4 * j];
      float invf = exp2f(-0.4152410118609203f * (float)j);  // 10000^(-j/32)
      float ang = fl * invf;
      float rev = ang * 0.15915494309189535f;
      rev = rev - floorf(rev);
      float sv, cv;
      __sincosf(rev * 6.2831853071795864f, &sv, &cv);
      qv[2 * p] = f2b(x4.x * cv - x4.z * sv);
      qv[2 * p + 1] = f2b(x4.x * sv + x4.z * cv);
      kv[2 * p] = f2b(x4.y * cv - x4.w * sv);
      kv[2 * p + 1] = f2b(x4.y * sv + x4.w * cv);
    }
    size_t base = ((size_t)(b * 512 + l)) * 64 + jb * 2;
    *(u16x4*)&qw[base] = qv;
    *(u16x4*)&kw[base] = kv;
  }

  // bias projection: (x @ W2 + b2)/2 ; thread (t<192): c = t>>3, rows (t&7)*2..+1
  if (t < 192) {
    int c = t >> 3;
    int rg = (t & 7) * 2;
    float s0 = b2[c], s1 = s0;
    #pragma unroll
    for (int k4 = 0; k4 < 32; ++k4) {
      float4 wv = *(const float4*)&w2t[c * 132 + k4 * 4];
      float4 x0 = *(const float4*)&xt[(rg + 0) * 132 + k4 * 4];
      float4 x1 = *(const float4*)&xt[(rg + 1) * 132 + k4 * 4];
      s0 += x0.x * wv.x + x0.y * wv.y + x0.z * wv.z + x0.w * wv.w;
      s1 += x1.x * wv.x + x1.y * wv.y + x1.z * wv.z + x1.w * wv.w;
    }
    int h = c >> 1;
    size_t o = ((size_t)(b * 12 + h)) * 512 + l0 + rg;
    float2 sv = {s0 * 0.5f, s1 * 0.5f};
    if (c & 1) *(float2*)&biasO[o] = sv;
    else       *(float2*)&biasE[o] = sv;
  }
}

// Kernel 2: 64x64 (m,n) tile per block, 12 heads. qk via MFMA on bf16 tiles.
__global__ __launch_bounds__(256) void k2_main(
    const u16* __restrict__ qw, const u16* __restrict__ kw,
    const float* __restrict__ biasE, const float* __restrict__ biasO,
    const float* __restrict__ amask, float* __restrict__ out) {
  __shared__ char smem[24448];
  u16* Q = (u16*)smem;              // 8KB swizzled [m][d]
  u16* K = (u16*)(smem + 8192);     // 8KB swizzled [n][d]
  float* qkL = (float*)smem;        // 64x68 f32 (17408B) — overlaps Q/K (dead)
  float* BN = (float*)(smem + 17408);
  float* BM = (float*)(smem + 17408 + 3264);
  float* AMm = (float*)(smem + 17408 + 6528);
  float* AMn = AMm + 64;

  int t = threadIdx.x;
  int lane = t & 63, w = t >> 6;
  int n0 = blockIdx.x * 64, m0 = blockIdx.y * 64, b = blockIdx.z;
  bool skip = (m0 >= n0 + 64);  // fully below diagonal

  if (!skip) {
    int row = t >> 2, sg = t & 3;
    const u16x8* qsrc = (const u16x8*)&qw[((size_t)(b * 512 + m0 + row)) * 64 + sg * 16];
    u16x8 q0 = qsrc[0], q1 = qsrc[1];
    const u16x8* ksrc = (const u16x8*)&kw[((size_t)(b * 512 + n0 + row)) * 64 + sg * 16];
    u16x8 k0v = ksrc[0], k1v = ksrc[1];
    int swz = (row & 7) << 4;
    int byt = row * 128 + sg * 32;
    *(u16x8*)((char*)Q + ((byt) ^ swz)) = q0;
    *(u16x8*)((char*)Q + ((byt + 16) ^ swz)) = q1;
    *(u16x8*)((char*)K + ((byt) ^ swz)) = k0v;
    *(u16x8*)((char*)K + ((byt + 16) ^ swz)) = k1v;
  }
  if (t < 192) {
    int h = t >> 4, kq = t & 15;
    *(float4*)&BN[h * 68 + kq * 4] =
        *(const float4*)&biasE[((size_t)(b * 12 + h)) * 512 + n0 + kq * 4];
    *(float4*)&BM[h * 68 + kq * 4] =
        *(const float4*)&biasO[((size_t)(b * 12 + h)) * 512 + m0 + kq * 4];
  } else if (t < 224) {
    int i = t - 192;
    if (i < 16) *(float4*)&AMm[i * 4] = *(const float4*)&amask[b * 512 + m0 + i * 4];
    else { int ii = i - 16; *(float4*)&AMn[ii * 4] = *(const float4*)&amask[b * 512 + n0 + ii * 4]; }
  }
  __syncthreads();

  if (!skip) {
    f32x4 acc[4];
    #pragma unroll
    for (int nt = 0; nt < 4; ++nt) acc[nt] = (f32x4){0.f, 0.f, 0.f, 0.f};
    int mrow = w * 16 + (lane & 15);
    int hi = lane >> 4;
    #pragma unroll
    for (int ks = 0; ks < 2; ++ks) {
      int cb = ks * 64 + hi * 16;
      bf16x8 a = *(const bf16x8*)((const char*)Q +
                                  ((mrow * 128 + cb) ^ ((mrow & 7) << 4)));
      #pragma unroll
      for (int nt = 0; nt < 4; ++nt) {
        int nr = nt * 16 + (lane & 15);
        bf16x8 bb = *(const bf16x8*)((const char*)K +
                                     ((nr * 128 + cb) ^ ((nr & 7) << 4)));
        acc[nt] = __builtin_amdgcn_mfma_f32_16x16x32_bf16(a, bb, acc[nt], 0, 0, 0);
      }
    }
    __syncthreads();  // Q/K dead; safe to overwrite with qkL
    #pragma unroll
    for (int nt = 0; nt < 4; ++nt)
      #pragma unroll
      for (int r = 0; r < 4; ++r)
        qkL[(w * 16 + hi * 4 + r) * 68 + nt * 16 + (lane & 15)] = acc[nt][r];
    __syncthreads();
  }

  int a15 = t & 15, mb = t >> 4;  // thread owns n = 4*a15+j, m = mb+16*mi
  float amn0 = AMn[a15 * 4 + 0], amn1 = AMn[a15 * 4 + 1];
  float amn2 = AMn[a15 * 4 + 2], amn3 = AMn[a15 * 4 + 3];
  float vals[4][4];
  #pragma unroll
  for (int mi = 0; mi < 4; ++mi) {
    int m = mb + 16 * mi;
    int mg = m0 + m;
    float amm = AMm[m];
    int ng = n0 + a15 * 4;
    float p0 = (1.f - amm * amn0) * FINF + ((mg > ng + 0) ? FINF : 0.f);
    float p1 = (1.f - amm * amn1) * FINF + ((mg > ng + 1) ? FINF : 0.f);
    float p2 = (1.f - amm * amn2) * FINF + ((mg > ng + 2) ? FINF : 0.f);
    float p3 = (1.f - amm * amn3) * FINF + ((mg > ng + 3) ? FINF : 0.f);
    if (!skip) {
      float4 qk = *(const float4*)&qkL[m * 68 + a15 * 4];
      vals[mi][0] = qk.x * 0.125f - p0;
      vals[mi][1] = qk.y * 0.125f - p1;
      vals[mi][2] = qk.z * 0.125f - p2;
      vals[mi][3] = qk.w * 0.125f - p3;
    } else {
      vals[mi][0] = -p0; vals[mi][1] = -p1; vals[mi][2] = -p2; vals[mi][3] = -p3;
    }
  }

  size_t outbase = (size_t)(b * 12) * 262144 + (size_t)m0 * 512 + n0 + a15 * 4;
  #pragma unroll
  for (int h = 0; h < 12; ++h) {
    float4 bn = *(const float4*)&BN[h * 68 + a15 * 4];
    #pragma unroll
    for (int mi = 0; mi < 4; ++mi) {
      int m = mb + 16 * mi;
      float bm = BM[h * 68 + m];
      float4 v;
      v.x = vals[mi][0] + bn.x + bm;
      v.y = vals[mi][1] + bn.y + bm;
      v.z = vals[mi][2] + bn.z + bm;
      v.w = vals[mi][3] + bn.w + bm;
      *(float4*)&out[outbase + (size_t)h * 262144 + (size_t)m * 512] = v;
    }
  }
}

extern "C" void kernel_launch(void* const* d_in, const int* in_sizes, int n_in,
                              void* d_out, int out_size, void* d_ws, size_t ws_size,
                              hipStream_t stream) {
  const float* inputs = (const float*)d_in[0];
  const float* amask  = (const float*)d_in[1];
  const float* W1     = (const float*)d_in[2];
  const float* b1     = (const float*)d_in[3];
  const float* W2     = (const float*)d_in[4];
  const float* b2     = (const float*)d_in[5];
  float* out = (float*)d_out;

  char* ws = (char*)d_ws;
  u16* qw      = (u16*)(ws);                            // 1 MB
  u16* kw      = (u16*)(ws + (1u << 20));               // 1 MB
  float* biasE = (float*)(ws + (2u << 20));             // 384 KB
  float* biasO = (float*)(ws + (2u << 20) + 393216u);   // 384 KB
  u16* w1f     = (u16*)(ws + (2u << 20) + 786432u);     // 256 KB

  k0_w1frag<<<512, 256, 0, stream>>>(W1, w1f);
  k1_prep<<<512, 256, 0, stream>>>(inputs, w1f, b1, W2, b2, qw, kw, biasE, biasO);
  k2_main<<<dim3(8, 8, 16), 256, 0, stream>>>(qw, kw, biasE, biasO, amask, out);
}